// Round 8
// baseline (118.509 us; speedup 1.0000x reference)
//
#include <hip/hip_runtime.h>

#define Bn 4096
#define Dn 66
#define Hn 512

typedef __attribute__((ext_vector_type(8))) short short8;
typedef __attribute__((ext_vector_type(4))) float f32x4;

__device__ __forceinline__ unsigned short f2bf(float x) {
    union { float f; unsigned u; } v; v.f = x;
    unsigned r = v.u + 0x7fffu + ((v.u >> 16) & 1u);   // RNE
    return (unsigned short)(r >> 16);
}
__device__ __forceinline__ float bf2f(unsigned short h) {
    union { float f; unsigned u; } v; v.u = ((unsigned)h) << 16; return v.f;
}

// Fragment-linear layouts (16x16x32 bf16 MFMA):
//   A-frag (block-local) tile ks: lane l holds A[(l&15)][ks*32 + (l>>4)*8 + j]
//       at (ks*64 + l)*8 + j                  -> conflict-free ds_read_b128
//   B-frag tile (ct, ks): lane l holds B[ks*32 + (l>>4)*8 + j][ct*16 + (l&15)]
//       at ((ct*16 + ks)*64 + l)*8 + j        -> 1KB contiguous global load per wave

// ============ k_pack: weight fragment packs only (74 blocks x 512) ============
// bid 0..63 : W2P + CmP   (one B-frag tile per wave; tix = ct*16 + ks)
// bid 64..73: W3P         (80 tiles incl. zero-padding to 80 cols)
__global__ __launch_bounds__(512, 2) void k_pack(
    const float* __restrict__ W1, const float* __restrict__ W2,
    const float* __restrict__ W3,
    unsigned short* __restrict__ W2P, unsigned short* __restrict__ CmP,
    unsigned short* __restrict__ W3P)
{
    const int bid = blockIdx.x, tid = threadIdx.x;
    const int lane = tid & 63, wv = tid >> 6;

    if (bid < 64) {
        const int tix = bid*8 + wv;
        const int ks = tix & 15;
        const int n = lane & 15, kg = lane >> 4;
        const int c = (tix >> 4)*16 + n;
        const int abase = ks*32 + kg*8;
        float w2v[8], m[8];
        #pragma unroll
        for (int j = 0; j < 8; ++j) {
            w2v[j] = W2[(size_t)(abase + j)*Hn + c];
            m[j] = 0.f;
        }
        for (int i = 0; i < Dn; ++i) {
            const float w3 = W3[(size_t)c*Dn + i];
            const float4 w1a = *(const float4*)&W1[(size_t)i*Hn + abase];
            const float4 w1b = *(const float4*)&W1[(size_t)i*Hn + abase + 4];
            m[0] = fmaf(w3, w1a.x, m[0]); m[1] = fmaf(w3, w1a.y, m[1]);
            m[2] = fmaf(w3, w1a.z, m[2]); m[3] = fmaf(w3, w1a.w, m[3]);
            m[4] = fmaf(w3, w1b.x, m[4]); m[5] = fmaf(w3, w1b.y, m[5]);
            m[6] = fmaf(w3, w1b.z, m[6]); m[7] = fmaf(w3, w1b.w, m[7]);
        }
        short8 pw, pc;
        #pragma unroll
        for (int j = 0; j < 8; ++j) {
            pw[j] = (short)f2bf(w2v[j]);
            pc[j] = (short)f2bf(w2v[j] * m[j]);
        }
        const size_t off = ((size_t)tix*64 + lane)*8;
        *(short8*)&W2P[off] = pw;
        *(short8*)&CmP[off] = pc;
    } else {
        const int tix = (bid - 64)*8 + wv;   // jt*16 + ks, 80 tiles
        if (tix < 80) {
            const int ks = tix & 15;
            const int n = lane & 15, kg = lane >> 4;
            const int j_out = (tix >> 4)*16 + n;
            const int abase = ks*32 + kg*8;
            short8 p;
            #pragma unroll
            for (int j = 0; j < 8; ++j)
                p[j] = (j_out < Dn) ? (short)f2bf(W3[(size_t)(abase + j)*Dn + j_out]) : (short)0;
            *(short8*)&W3P[((size_t)tix*64 + lane)*8] = p;
        }
    }
}

// ============ k_main: fully fused per-16-row tile (grid 256 x 512 thr) ============
// phase A: fp32 K=67 GEMM -> h1 hi/lo + s1' A-frags in LDS
// phase B: MFMA z2 = h1@W2 + b2, v = s1'@Cmat (A from LDS, weights 1KB global loads)
// epilogue: silu -> h2 hi/lo to separate LDS region + divergence partials
// phase C: MFMA out = h2@W3 + b3; divergence finalize. No global activation traffic.
__global__ __launch_bounds__(512, 2) void k_main(
    const float* __restrict__ xs, const float* __restrict__ tt,
    const float* __restrict__ W1, const float* __restrict__ b1,
    const unsigned short* __restrict__ W2P, const unsigned short* __restrict__ CmP,
    const float* __restrict__ b2,
    const unsigned short* __restrict__ W3P, const float* __restrict__ b3,
    float* __restrict__ out)
{
    __shared__ __align__(16) unsigned short sA[3*8192];  // h1hi | h1lo | s1' (48 KB)
    __shared__ __align__(16) unsigned short sH[8192];    // h2 hi (16 KB)
    __shared__ __align__(16) unsigned short sL[8192];    // h2 lo (16 KB)
    __shared__ float sX[67*16];
    __shared__ float sRed[8*16];

    const int tid = threadIdx.x, lane = tid & 63, wv = tid >> 6;
    const int rt = blockIdx.x, r0 = rt*16;
    const int n = lane & 15, kg = lane >> 4;

    // ---- stage x^T (row 66 = t) ----
    for (int idx = tid; idx < 67*16; idx += 512) {
        const int i = idx >> 4, r = idx & 15;
        sX[idx] = (i < Dn) ? xs[(size_t)(r0+r)*Dn + i] : tt[r0+r];
    }
    __syncthreads();

    // ---- phase A: z1 (fp32), rows {2rg,2rg+1}, cols cA..cA+3 / cB..cB+3 ----
    {
        const int rg = lane & 7, cg = lane >> 3;
        const int cA = wv*64 + cg*4, cB = cA + 32;
        float z[2][8];
        {
            const float4 bA4 = *(const float4*)&b1[cA];
            const float4 bB4 = *(const float4*)&b1[cB];
            const float bb[8] = {bA4.x,bA4.y,bA4.z,bA4.w, bB4.x,bB4.y,bB4.z,bB4.w};
            #pragma unroll
            for (int j = 0; j < 8; ++j) { z[0][j] = bb[j]; z[1][j] = bb[j]; }
        }
        for (int i = 0; i < 67; ++i) {
            const float2 xf = *(const float2*)&sX[i*16 + 2*rg];
            const float4 wA = *(const float4*)&W1[(size_t)i*Hn + cA];
            const float4 wB = *(const float4*)&W1[(size_t)i*Hn + cB];
            const float ww[8] = {wA.x,wA.y,wA.z,wA.w, wB.x,wB.y,wB.z,wB.w};
            #pragma unroll
            for (int j = 0; j < 8; ++j) {
                z[0][j] = fmaf(xf.x, ww[j], z[0][j]);
                z[1][j] = fmaf(xf.y, ww[j], z[1][j]);
            }
        }
        const int kgrp = cg >> 1, joff = (cg & 1)*4;
        #pragma unroll
        for (int rr = 0; rr < 2; ++rr) {
            const int r = 2*rg + rr;
            #pragma unroll
            for (int grp = 0; grp < 2; ++grp) {
                ushort4 phi, plo, ps;
                unsigned short* PH = (unsigned short*)&phi;
                unsigned short* PL = (unsigned short*)&plo;
                unsigned short* PS = (unsigned short*)&ps;
                #pragma unroll
                for (int j = 0; j < 4; ++j) {
                    const float zv = z[rr][grp*4 + j];
                    const float sg = 1.f / (1.f + __expf(-zv));
                    const float h  = zv * sg;
                    const float sp = sg * (1.f + zv * (1.f - sg));
                    const unsigned short hh = f2bf(h);
                    PH[j] = hh;
                    PL[j] = f2bf(h - bf2f(hh));
                    PS[j] = f2bf(sp);
                }
                const int ks = 2*wv + grp;
                const int off = (ks*64 + r + 16*kgrp)*8 + joff;
                *(ushort4*)&sA[off]          = phi;
                *(ushort4*)&sA[8192 + off]   = plo;
                *(ushort4*)&sA[16384 + off]  = ps;
            }
        }
    }
    __syncthreads();

    // ---- phase B: z2/v MFMA; A-frags from LDS, weights coalesced from L2 ----
    const int ctb = wv*4;                    // cols [wv*64, wv*64+64)
    f32x4 zac[4], vac[4];
    #pragma unroll
    for (int ti = 0; ti < 4; ++ti) {
        const float bz = b2[(ctb + ti)*16 + n];
        zac[ti] = (f32x4){bz, bz, bz, bz};
        vac[ti] = (f32x4){0.f, 0.f, 0.f, 0.f};
    }
    #pragma unroll 2
    for (int ks = 0; ks < 16; ++ks) {
        const int ao = (ks*64 + lane)*8;
        const short8 ahi = *(const short8*)&sA[ao];
        const short8 alo = *(const short8*)&sA[8192 + ao];
        const short8 as1 = *(const short8*)&sA[16384 + ao];
        #pragma unroll
        for (int ti = 0; ti < 4; ++ti) {
            const size_t wo = ((size_t)((ctb + ti)*16 + ks)*64 + lane)*8;
            const short8 wf = *(const short8*)&W2P[wo];
            const short8 qf = *(const short8*)&CmP[wo];
            zac[ti] = __builtin_amdgcn_mfma_f32_16x16x32_bf16(ahi, wf, zac[ti], 0, 0, 0);
            zac[ti] = __builtin_amdgcn_mfma_f32_16x16x32_bf16(alo, wf, zac[ti], 0, 0, 0);
            vac[ti] = __builtin_amdgcn_mfma_f32_16x16x32_bf16(as1, qf, vac[ti], 0, 0, 0);
        }
    }

    // ---- epilogue: h2 hi/lo -> sH/sL (separate region, no barrier needed), dp ----
    float dp[4] = {0.f, 0.f, 0.f, 0.f};
    #pragma unroll
    for (int ti = 0; ti < 4; ++ti) {
        const int c = (ctb + ti)*16 + n;
        const int ks2 = c >> 5, kg2 = (c >> 3) & 3, j2 = c & 7;
        #pragma unroll
        for (int q = 0; q < 4; ++q) {
            const float z2 = zac[ti][q];
            const float sg = 1.f / (1.f + __expf(-z2));
            const float h2 = z2 * sg;
            dp[q] = fmaf(sg * (1.f + z2 * (1.f - sg)), vac[ti][q], dp[q]);
            const unsigned short hh = f2bf(h2);
            const int o = (ks2*64 + (kg*4 + q) + 16*kg2)*8 + j2;
            sH[o] = hh;
            sL[o] = f2bf(h2 - bf2f(hh));
        }
    }
    #pragma unroll
    for (int q = 0; q < 4; ++q) {
        float v = dp[q];
        v += __shfl_xor(v, 1, 64);
        v += __shfl_xor(v, 2, 64);
        v += __shfl_xor(v, 4, 64);
        v += __shfl_xor(v, 8, 64);
        if (n == 0) sRed[wv*16 + kg*4 + q] = v;
    }
    __syncthreads();

    // ---- divergence finalize ----
    if (tid < 16) {
        float s = 0.f;
        #pragma unroll
        for (int q = 0; q < 8; ++q) s += sRed[q*16 + tid];
        out[(size_t)Bn*Dn + r0 + tid] = -s;
    }

    // ---- phase C: out = h2 @ W3 + b3 (waves 0..4, one 16-col j-tile each) ----
    if (wv < 5) {
        const int jt = wv;
        const int j = jt*16 + n;
        const float bj = (j < Dn) ? b3[j] : 0.f;
        f32x4 oac = (f32x4){bj, bj, bj, bj};
        #pragma unroll 4
        for (int ks = 0; ks < 16; ++ks) {
            const int aoff = (ks*64 + lane)*8;
            const short8 ahi = *(const short8*)&sH[aoff];
            const short8 alo = *(const short8*)&sL[aoff];
            const short8 wf  = *(const short8*)&W3P[((size_t)(jt*16 + ks)*64 + lane)*8];
            oac = __builtin_amdgcn_mfma_f32_16x16x32_bf16(ahi, wf, oac, 0, 0, 0);
            oac = __builtin_amdgcn_mfma_f32_16x16x32_bf16(alo, wf, oac, 0, 0, 0);
        }
        if (j < Dn) {
            #pragma unroll
            for (int q = 0; q < 4; ++q)
                out[(size_t)(r0 + kg*4 + q)*Dn + j] = oac[q];
        }
    }
}

extern "C" void kernel_launch(void* const* d_in, const int* in_sizes, int n_in,
                              void* d_out, int out_size, void* d_ws, size_t ws_size,
                              hipStream_t stream)
{
    const float* xs = (const float*)d_in[0];
    const float* t  = (const float*)d_in[1];
    const float* W1 = (const float*)d_in[2];
    const float* b1 = (const float*)d_in[3];
    const float* W2 = (const float*)d_in[4];
    const float* b2 = (const float*)d_in[5];
    const float* W3 = (const float*)d_in[6];
    const float* b3 = (const float*)d_in[7];
    float* out = (float*)d_out;

    char* ws = (char*)d_ws;
    unsigned short* W2P = (unsigned short*)(ws);                 // 512 KB
    unsigned short* CmP = (unsigned short*)(ws + 524288);        // 512 KB
    unsigned short* W3P = (unsigned short*)(ws + 1048576);       // 80 KB

    k_pack<<<74,  512, 0, stream>>>(W1, W2, W3, W2P, CmP, W3P);
    k_main<<<256, 512, 0, stream>>>(xs, t, W1, b1, W2P, CmP, b2, W3P, b3, out);
}

// Round 9
// 115.055 us; speedup vs baseline: 1.0300x; 1.0300x over previous
//
#include <hip/hip_runtime.h>

#define Bn 4096
#define Dn 66
#define Hn 512

typedef __attribute__((ext_vector_type(8))) short short8;
typedef __attribute__((ext_vector_type(4))) float f32x4;

__device__ __forceinline__ unsigned short f2bf(float x) {
    union { float f; unsigned u; } v; v.f = x;
    unsigned r = v.u + 0x7fffu + ((v.u >> 16) & 1u);   // RNE
    return (unsigned short)(r >> 16);
}
__device__ __forceinline__ float bf2f(unsigned short h) {
    union { float f; unsigned u; } v; v.u = ((unsigned)h) << 16; return v.f;
}

// Fragment-linear layouts (16x16x32 bf16 MFMA):
//   A-frag (block-local) tile ks: lane l holds A[(l&15)][ks*32 + (l>>4)*8 + j]
//       at (ks*64 + l)*8 + j                  -> conflict-free ds_read_b128
//   B-frag tile (ct, ks): lane l holds B[ks*32 + (l>>4)*8 + j][ct*16 + (l&15)]
//       at ((ct*16 + ks)*64 + l)*8 + j        -> 1KB contiguous global load per wave

// ============ k_pack (74 blocks x 512) ============
// bid 0..63 : W2P + CmP. Block covers ct = bid>>1 (cols [ct*16,ct*16+16)), waves own
//             ks = (bid&1)*8 + wv. W3 rows for the 16 cols staged coalesced in LDS.
// bid 64..73: W3P (80 tiles incl. zero-pad to 80 cols).
__global__ __launch_bounds__(512, 2) void k_pack(
    const float* __restrict__ W1, const float* __restrict__ W2,
    const float* __restrict__ W3,
    unsigned short* __restrict__ W2P, unsigned short* __restrict__ CmP,
    unsigned short* __restrict__ W3P)
{
    __shared__ float sW3[16*68];
    const int bid = blockIdx.x, tid = threadIdx.x;
    const int lane = tid & 63, wv = tid >> 6;

    if (bid < 64) {
        const int ct = bid >> 1;
        // stage W3 rows [ct*16, ct*16+16) coalesced
        {
            const int r = tid >> 5, ii = tid & 31;   // 512 thr = 16 rows x 32
            const float* src = &W3[(size_t)(ct*16 + r)*Dn];
            sW3[r*68 + ii] = src[ii];
            sW3[r*68 + ii + 32] = src[ii + 32];
            if (ii < 2) sW3[r*68 + ii + 64] = src[ii + 64];
        }
        __syncthreads();
        const int ks = (bid & 1)*8 + wv;
        const int n = lane & 15, kg = lane >> 4;
        const int c = ct*16 + n;
        const int abase = ks*32 + kg*8;
        float w2v[8], m[8];
        #pragma unroll
        for (int j = 0; j < 8; ++j) {
            w2v[j] = W2[(size_t)(abase + j)*Hn + c];
            m[j] = 0.f;
        }
        #pragma unroll 2
        for (int i = 0; i < Dn; ++i) {
            const float w3 = sW3[n*68 + i];                      // broadcast, 2-way-bank free
            const float4 w1a = *(const float4*)&W1[(size_t)i*Hn + abase];
            const float4 w1b = *(const float4*)&W1[(size_t)i*Hn + abase + 4];
            m[0] = fmaf(w3, w1a.x, m[0]); m[1] = fmaf(w3, w1a.y, m[1]);
            m[2] = fmaf(w3, w1a.z, m[2]); m[3] = fmaf(w3, w1a.w, m[3]);
            m[4] = fmaf(w3, w1b.x, m[4]); m[5] = fmaf(w3, w1b.y, m[5]);
            m[6] = fmaf(w3, w1b.z, m[6]); m[7] = fmaf(w3, w1b.w, m[7]);
        }
        short8 pw, pc;
        #pragma unroll
        for (int j = 0; j < 8; ++j) {
            pw[j] = (short)f2bf(w2v[j]);
            pc[j] = (short)f2bf(w2v[j] * m[j]);
        }
        const size_t off = ((size_t)(ct*16 + ks)*64 + lane)*8;
        *(short8*)&W2P[off] = pw;
        *(short8*)&CmP[off] = pc;
    } else {
        const int tix = (bid - 64)*8 + wv;   // jt*16 + ks, 80 tiles
        if (tix < 80) {
            const int ks = tix & 15;
            const int n = lane & 15, kg = lane >> 4;
            const int j_out = (tix >> 4)*16 + n;
            const int abase = ks*32 + kg*8;
            short8 p;
            #pragma unroll
            for (int j = 0; j < 8; ++j)
                p[j] = (j_out < Dn) ? (short)f2bf(W3[(size_t)(abase + j)*Dn + j_out]) : (short)0;
            *(short8*)&W3P[((size_t)tix*64 + lane)*8] = p;
        }
    }
}

// ============ k_main: fully fused, grid 256 x 1024 thr (16 waves/CU) ============
// phase A: fp32 K=67 GEMM -> h1 hi/lo + s1' A-frags in LDS (wave wv owns ks-tile wv)
// phase B: MFMA z2/v; A-frags broadcast from LDS; each wave 2 ctiles (32 cols)
// epilogue: h2 hi/lo aliased into dead h1 LDS region; divergence partials
// phase C: MFMA out = h2@W3 + b3 (waves 0..4); divergence finalize.
__global__ __launch_bounds__(1024, 4) void k_main(
    const float* __restrict__ xs, const float* __restrict__ tt,
    const float* __restrict__ W1, const float* __restrict__ b1,
    const unsigned short* __restrict__ W2P, const unsigned short* __restrict__ CmP,
    const float* __restrict__ b2,
    const unsigned short* __restrict__ W3P, const float* __restrict__ b3,
    float* __restrict__ out)
{
    __shared__ __align__(16) unsigned short sA[3*8192];  // h1hi|h1lo|s1' ; then h2hi|h2lo
    __shared__ float sX[67*16];
    __shared__ float sRed[16*16];

    const int tid = threadIdx.x, lane = tid & 63, wv = tid >> 6;   // wv 0..15
    const int rt = blockIdx.x, r0 = rt*16;
    const int n = lane & 15, kg = lane >> 4;

    // ---- stage x^T (row 66 = t) ----
    for (int idx = tid; idx < 67*16; idx += 1024) {
        const int i = idx >> 4, r = idx & 15;
        sX[idx] = (i < Dn) ? xs[(size_t)(r0+r)*Dn + i] : tt[r0+r];
    }
    __syncthreads();

    // ---- phase A: z1 (fp32); wave wv owns cols [wv*32, wv*32+32) = ks-tile wv ----
    {
        const int rg = lane & 7, cg = lane >> 3;
        const int c0 = wv*32 + cg*4;
        float z[2][4];
        {
            const float4 b4 = *(const float4*)&b1[c0];
            z[0][0]=b4.x; z[0][1]=b4.y; z[0][2]=b4.z; z[0][3]=b4.w;
            z[1][0]=b4.x; z[1][1]=b4.y; z[1][2]=b4.z; z[1][3]=b4.w;
        }
        #pragma unroll 2
        for (int i = 0; i < 67; ++i) {
            const float2 xf = *(const float2*)&sX[i*16 + 2*rg];
            const float4 wA = *(const float4*)&W1[(size_t)i*Hn + c0];
            const float ww[4] = {wA.x, wA.y, wA.z, wA.w};
            #pragma unroll
            for (int j = 0; j < 4; ++j) {
                z[0][j] = fmaf(xf.x, ww[j], z[0][j]);
                z[1][j] = fmaf(xf.y, ww[j], z[1][j]);
            }
        }
        const int kgrp = cg >> 1, joff = (cg & 1)*4;
        #pragma unroll
        for (int rr = 0; rr < 2; ++rr) {
            const int r = 2*rg + rr;
            ushort4 phi, plo, ps;
            unsigned short* PH = (unsigned short*)&phi;
            unsigned short* PL = (unsigned short*)&plo;
            unsigned short* PS = (unsigned short*)&ps;
            #pragma unroll
            for (int j = 0; j < 4; ++j) {
                const float zv = z[rr][j];
                const float sg = 1.f / (1.f + __expf(-zv));
                const float h  = zv * sg;
                const float sp = sg * (1.f + zv * (1.f - sg));
                const unsigned short hh = f2bf(h);
                PH[j] = hh;
                PL[j] = f2bf(h - bf2f(hh));
                PS[j] = f2bf(sp);
            }
            const int off = (wv*64 + r + 16*kgrp)*8 + joff;
            *(ushort4*)&sA[off]         = phi;
            *(ushort4*)&sA[8192 + off]  = plo;
            *(ushort4*)&sA[16384 + off] = ps;
        }
    }
    __syncthreads();

    // ---- phase B: z2/v MFMA; wave wv -> ctiles {wv*2, wv*2+1} ----
    const int ctb = wv*2;
    f32x4 zac[2], vac[2];
    #pragma unroll
    for (int ti = 0; ti < 2; ++ti) {
        const float bz = b2[(ctb + ti)*16 + n];
        zac[ti] = (f32x4){bz, bz, bz, bz};
        vac[ti] = (f32x4){0.f, 0.f, 0.f, 0.f};
    }
    #pragma unroll 2
    for (int ks = 0; ks < 16; ++ks) {
        const int ao = (ks*64 + lane)*8;
        const short8 ahi = *(const short8*)&sA[ao];
        const short8 alo = *(const short8*)&sA[8192 + ao];
        const short8 as1 = *(const short8*)&sA[16384 + ao];
        #pragma unroll
        for (int ti = 0; ti < 2; ++ti) {
            const size_t wo = ((size_t)((ctb + ti)*16 + ks)*64 + lane)*8;
            const short8 wf = *(const short8*)&W2P[wo];
            const short8 qf = *(const short8*)&CmP[wo];
            zac[ti] = __builtin_amdgcn_mfma_f32_16x16x32_bf16(ahi, wf, zac[ti], 0, 0, 0);
            zac[ti] = __builtin_amdgcn_mfma_f32_16x16x32_bf16(alo, wf, zac[ti], 0, 0, 0);
            vac[ti] = __builtin_amdgcn_mfma_f32_16x16x32_bf16(as1, qf, vac[ti], 0, 0, 0);
        }
    }
    __syncthreads();   // all sA reads complete before h2 aliases it

    // ---- epilogue: h2 hi/lo -> sA[0..8192] / sA[8192..16384]; divergence partials ----
    float dp[4] = {0.f, 0.f, 0.f, 0.f};
    #pragma unroll
    for (int ti = 0; ti < 2; ++ti) {
        const int c = (ctb + ti)*16 + n;
        const int ks2 = c >> 5, kg2 = (c >> 3) & 3, j2 = c & 7;
        #pragma unroll
        for (int q = 0; q < 4; ++q) {
            const float z2 = zac[ti][q];
            const float sg = 1.f / (1.f + __expf(-z2));
            const float h2 = z2 * sg;
            dp[q] = fmaf(sg * (1.f + z2 * (1.f - sg)), vac[ti][q], dp[q]);
            const unsigned short hh = f2bf(h2);
            const int o = (ks2*64 + (kg*4 + q) + 16*kg2)*8 + j2;
            sA[o] = hh;
            sA[8192 + o] = f2bf(h2 - bf2f(hh));
        }
    }
    #pragma unroll
    for (int q = 0; q < 4; ++q) {
        float v = dp[q];
        v += __shfl_xor(v, 1, 64);
        v += __shfl_xor(v, 2, 64);
        v += __shfl_xor(v, 4, 64);
        v += __shfl_xor(v, 8, 64);
        if (n == 0) sRed[wv*16 + kg*4 + q] = v;
    }
    __syncthreads();

    // ---- divergence finalize ----
    if (tid < 16) {
        float s = 0.f;
        #pragma unroll
        for (int q = 0; q < 16; ++q) s += sRed[q*16 + tid];
        out[(size_t)Bn*Dn + r0 + tid] = -s;
    }

    // ---- phase C: out = h2 @ W3 + b3 (waves 0..4, one 16-col j-tile each) ----
    if (wv < 5) {
        const int jt = wv;
        const int j = jt*16 + n;
        const float bj = (j < Dn) ? b3[j] : 0.f;
        f32x4 oac = (f32x4){bj, bj, bj, bj};
        #pragma unroll 4
        for (int ks = 0; ks < 16; ++ks) {
            const int aoff = (ks*64 + lane)*8;
            const short8 ahi = *(const short8*)&sA[aoff];
            const short8 alo = *(const short8*)&sA[8192 + aoff];
            const short8 wf  = *(const short8*)&W3P[((size_t)(jt*16 + ks)*64 + lane)*8];
            oac = __builtin_amdgcn_mfma_f32_16x16x32_bf16(ahi, wf, oac, 0, 0, 0);
            oac = __builtin_amdgcn_mfma_f32_16x16x32_bf16(alo, wf, oac, 0, 0, 0);
        }
        if (j < Dn) {
            #pragma unroll
            for (int q = 0; q < 4; ++q)
                out[(size_t)(r0 + kg*4 + q)*Dn + j] = oac[q];
        }
    }
}

extern "C" void kernel_launch(void* const* d_in, const int* in_sizes, int n_in,
                              void* d_out, int out_size, void* d_ws, size_t ws_size,
                              hipStream_t stream)
{
    const float* xs = (const float*)d_in[0];
    const float* t  = (const float*)d_in[1];
    const float* W1 = (const float*)d_in[2];
    const float* b1 = (const float*)d_in[3];
    const float* W2 = (const float*)d_in[4];
    const float* b2 = (const float*)d_in[5];
    const float* W3 = (const float*)d_in[6];
    const float* b3 = (const float*)d_in[7];
    float* out = (float*)d_out;

    char* ws = (char*)d_ws;
    unsigned short* W2P = (unsigned short*)(ws);                 // 512 KB
    unsigned short* CmP = (unsigned short*)(ws + 524288);        // 512 KB
    unsigned short* W3P = (unsigned short*)(ws + 1048576);       // 80 KB

    k_pack<<<74,  512,  0, stream>>>(W1, W2, W3, W2P, CmP, W3P);
    k_main<<<256, 1024, 0, stream>>>(xs, t, W1, b1, W2P, CmP, b2, W3P, b3, out);
}

// Round 10
// 106.552 us; speedup vs baseline: 1.1122x; 1.0798x over previous
//
#include <hip/hip_runtime.h>

#define Bn 4096
#define Dn 66
#define Hn 512

typedef __attribute__((ext_vector_type(8))) short short8;
typedef __attribute__((ext_vector_type(4))) float f32x4;

__device__ __forceinline__ unsigned short f2bf(float x) {
    union { float f; unsigned u; } v; v.f = x;
    unsigned r = v.u + 0x7fffu + ((v.u >> 16) & 1u);   // RNE
    return (unsigned short)(r >> 16);
}
__device__ __forceinline__ float bf2f(unsigned short h) {
    union { float f; unsigned u; } v; v.u = ((unsigned)h) << 16; return v.f;
}

// Fragment-linear layouts (16x16x32 bf16 MFMA):
//   A-frag (block-local) tile ks: lane l holds A[(l&15)][ks*32 + (l>>4)*8 + j]
//       at (ks*64 + l)*8 + j                  -> conflict-free ds_read_b128
//   B-frag tile (ct, ks): lane l holds B[ks*32 + (l>>4)*8 + j][ct*16 + (l&15)]
//       at ((ct*16 + ks)*64 + l)*8 + j        -> 1KB contiguous global load per wave

// ============ k_pack (74 blocks x 512) — unchanged from R9 ============
__global__ __launch_bounds__(512, 2) void k_pack(
    const float* __restrict__ W1, const float* __restrict__ W2,
    const float* __restrict__ W3,
    unsigned short* __restrict__ W2P, unsigned short* __restrict__ CmP,
    unsigned short* __restrict__ W3P)
{
    __shared__ float sW3[16*68];
    const int bid = blockIdx.x, tid = threadIdx.x;
    const int lane = tid & 63, wv = tid >> 6;

    if (bid < 64) {
        const int ct = bid >> 1;
        {
            const int r = tid >> 5, ii = tid & 31;
            const float* src = &W3[(size_t)(ct*16 + r)*Dn];
            sW3[r*68 + ii] = src[ii];
            sW3[r*68 + ii + 32] = src[ii + 32];
            if (ii < 2) sW3[r*68 + ii + 64] = src[ii + 64];
        }
        __syncthreads();
        const int ks = (bid & 1)*8 + wv;
        const int n = lane & 15, kg = lane >> 4;
        const int c = ct*16 + n;
        const int abase = ks*32 + kg*8;
        float w2v[8], m[8];
        #pragma unroll
        for (int j = 0; j < 8; ++j) {
            w2v[j] = W2[(size_t)(abase + j)*Hn + c];
            m[j] = 0.f;
        }
        #pragma unroll 2
        for (int i = 0; i < Dn; ++i) {
            const float w3 = sW3[n*68 + i];
            const float4 w1a = *(const float4*)&W1[(size_t)i*Hn + abase];
            const float4 w1b = *(const float4*)&W1[(size_t)i*Hn + abase + 4];
            m[0] = fmaf(w3, w1a.x, m[0]); m[1] = fmaf(w3, w1a.y, m[1]);
            m[2] = fmaf(w3, w1a.z, m[2]); m[3] = fmaf(w3, w1a.w, m[3]);
            m[4] = fmaf(w3, w1b.x, m[4]); m[5] = fmaf(w3, w1b.y, m[5]);
            m[6] = fmaf(w3, w1b.z, m[6]); m[7] = fmaf(w3, w1b.w, m[7]);
        }
        short8 pw, pc;
        #pragma unroll
        for (int j = 0; j < 8; ++j) {
            pw[j] = (short)f2bf(w2v[j]);
            pc[j] = (short)f2bf(w2v[j] * m[j]);
        }
        const size_t off = ((size_t)(ct*16 + ks)*64 + lane)*8;
        *(short8*)&W2P[off] = pw;
        *(short8*)&CmP[off] = pc;
    } else {
        const int tix = (bid - 64)*8 + wv;
        if (tix < 80) {
            const int ks = tix & 15;
            const int n = lane & 15, kg = lane >> 4;
            const int j_out = (tix >> 4)*16 + n;
            const int abase = ks*32 + kg*8;
            short8 p;
            #pragma unroll
            for (int j = 0; j < 8; ++j)
                p[j] = (j_out < Dn) ? (short)f2bf(W3[(size_t)(abase + j)*Dn + j_out]) : (short)0;
            *(short8*)&W3P[((size_t)tix*64 + lane)*8] = p;
        }
    }
}

// ============ k_main: fused, grid 256 x 1024; per-block address-stream rotation ============
__global__ __launch_bounds__(1024, 4) void k_main(
    const float* __restrict__ xs, const float* __restrict__ tt,
    const float* __restrict__ W1, const float* __restrict__ b1,
    const unsigned short* __restrict__ W2P, const unsigned short* __restrict__ CmP,
    const float* __restrict__ b2,
    const unsigned short* __restrict__ W3P, const float* __restrict__ b3,
    float* __restrict__ out)
{
    __shared__ __align__(16) unsigned short sA[3*8192];  // h1hi|h1lo|s1' ; then h2hi|h2lo
    __shared__ float sX[67*16];
    __shared__ float sRed[16*16];

    const int tid = threadIdx.x, lane = tid & 63, wv = tid >> 6;   // wv 0..15
    const int rt = blockIdx.x, r0 = rt*16;
    const int n = lane & 15, kg = lane >> 4;
    const int rot = (blockIdx.x >> 3) & 15;       // 16 distinct phases within an XCD

    // ---- stage x^T (row 66 = t) ----
    for (int idx = tid; idx < 67*16; idx += 1024) {
        const int i = idx >> 4, r = idx & 15;
        sX[idx] = (i < Dn) ? xs[(size_t)(r0+r)*Dn + i] : tt[r0+r];
    }
    __syncthreads();

    // ---- phase A: z1 (fp32); wave wv owns cols [wv*32, wv*32+32); rotated i-start ----
    {
        const int rg = lane & 7, cg = lane >> 3;
        const int c0 = wv*32 + cg*4;
        const int irot = (blockIdx.x >> 3) & 31;  // de-correlate W1 row stream
        float z[2][4];
        {
            const float4 b4 = *(const float4*)&b1[c0];
            z[0][0]=b4.x; z[0][1]=b4.y; z[0][2]=b4.z; z[0][3]=b4.w;
            z[1][0]=b4.x; z[1][1]=b4.y; z[1][2]=b4.z; z[1][3]=b4.w;
        }
        #pragma unroll 2
        for (int s = 0; s < 67; ++s) {
            int i = s + irot; if (i >= 67) i -= 67;
            const float2 xf = *(const float2*)&sX[i*16 + 2*rg];
            const float4 wA = *(const float4*)&W1[(size_t)i*Hn + c0];
            const float ww[4] = {wA.x, wA.y, wA.z, wA.w};
            #pragma unroll
            for (int j = 0; j < 4; ++j) {
                z[0][j] = fmaf(xf.x, ww[j], z[0][j]);
                z[1][j] = fmaf(xf.y, ww[j], z[1][j]);
            }
        }
        const int kgrp = cg >> 1, joff = (cg & 1)*4;
        #pragma unroll
        for (int rr = 0; rr < 2; ++rr) {
            const int r = 2*rg + rr;
            ushort4 phi, plo, ps;
            unsigned short* PH = (unsigned short*)&phi;
            unsigned short* PL = (unsigned short*)&plo;
            unsigned short* PS = (unsigned short*)&ps;
            #pragma unroll
            for (int j = 0; j < 4; ++j) {
                const float zv = z[rr][j];
                const float sg = 1.f / (1.f + __expf(-zv));
                const float h  = zv * sg;
                const float sp = sg * (1.f + zv * (1.f - sg));
                const unsigned short hh = f2bf(h);
                PH[j] = hh;
                PL[j] = f2bf(h - bf2f(hh));
                PS[j] = f2bf(sp);
            }
            const int off = (wv*64 + r + 16*kgrp)*8 + joff;
            *(ushort4*)&sA[off]         = phi;
            *(ushort4*)&sA[8192 + off]  = plo;
            *(ushort4*)&sA[16384 + off] = ps;
        }
    }
    __syncthreads();

    // ---- phase B: z2/v MFMA; wave wv -> ctiles {wv*2, wv*2+1}; rotated ks ----
    const int ctb = wv*2;
    f32x4 zac[2], vac[2];
    #pragma unroll
    for (int ti = 0; ti < 2; ++ti) {
        const float bz = b2[(ctb + ti)*16 + n];
        zac[ti] = (f32x4){bz, bz, bz, bz};
        vac[ti] = (f32x4){0.f, 0.f, 0.f, 0.f};
    }
    #pragma unroll 2
    for (int s = 0; s < 16; ++s) {
        const int ks = (s + rot) & 15;
        const int ao = (ks*64 + lane)*8;
        const short8 ahi = *(const short8*)&sA[ao];
        const short8 alo = *(const short8*)&sA[8192 + ao];
        const short8 as1 = *(const short8*)&sA[16384 + ao];
        #pragma unroll
        for (int ti = 0; ti < 2; ++ti) {
            const size_t wo = ((size_t)((ctb + ti)*16 + ks)*64 + lane)*8;
            const short8 wf = *(const short8*)&W2P[wo];
            const short8 qf = *(const short8*)&CmP[wo];
            zac[ti] = __builtin_amdgcn_mfma_f32_16x16x32_bf16(ahi, wf, zac[ti], 0, 0, 0);
            zac[ti] = __builtin_amdgcn_mfma_f32_16x16x32_bf16(alo, wf, zac[ti], 0, 0, 0);
            vac[ti] = __builtin_amdgcn_mfma_f32_16x16x32_bf16(as1, qf, vac[ti], 0, 0, 0);
        }
    }
    __syncthreads();   // all sA reads complete before h2 aliases it

    // ---- epilogue: h2 hi/lo -> sA[0..8192]/sA[8192..]; divergence partials ----
    float dp[4] = {0.f, 0.f, 0.f, 0.f};
    #pragma unroll
    for (int ti = 0; ti < 2; ++ti) {
        const int c = (ctb + ti)*16 + n;
        const int ks2 = c >> 5, kg2 = (c >> 3) & 3, j2 = c & 7;
        #pragma unroll
        for (int q = 0; q < 4; ++q) {
            const float z2 = zac[ti][q];
            const float sg = 1.f / (1.f + __expf(-z2));
            const float h2 = z2 * sg;
            dp[q] = fmaf(sg * (1.f + z2 * (1.f - sg)), vac[ti][q], dp[q]);
            const unsigned short hh = f2bf(h2);
            const int o = (ks2*64 + (kg*4 + q) + 16*kg2)*8 + j2;
            sA[o] = hh;
            sA[8192 + o] = f2bf(h2 - bf2f(hh));
        }
    }
    #pragma unroll
    for (int q = 0; q < 4; ++q) {
        float v = dp[q];
        v += __shfl_xor(v, 1, 64);
        v += __shfl_xor(v, 2, 64);
        v += __shfl_xor(v, 4, 64);
        v += __shfl_xor(v, 8, 64);
        if (n == 0) sRed[wv*16 + kg*4 + q] = v;
    }
    __syncthreads();

    // ---- divergence finalize ----
    if (tid < 16) {
        float s = 0.f;
        #pragma unroll
        for (int q = 0; q < 16; ++q) s += sRed[q*16 + tid];
        out[(size_t)Bn*Dn + r0 + tid] = -s;
    }

    // ---- phase C: out = h2 @ W3 + b3 (waves 0..4); rotated ks ----
    if (wv < 5) {
        const int jt = wv;
        const int j = jt*16 + n;
        const float bj = (j < Dn) ? b3[j] : 0.f;
        f32x4 oac = (f32x4){bj, bj, bj, bj};
        #pragma unroll 4
        for (int s = 0; s < 16; ++s) {
            const int ks = (s + rot) & 15;
            const int aoff = (ks*64 + lane)*8;
            const short8 ahi = *(const short8*)&sA[aoff];
            const short8 alo = *(const short8*)&sA[8192 + aoff];
            const short8 wf  = *(const short8*)&W3P[((size_t)(jt*16 + ks)*64 + lane)*8];
            oac = __builtin_amdgcn_mfma_f32_16x16x32_bf16(ahi, wf, oac, 0, 0, 0);
            oac = __builtin_amdgcn_mfma_f32_16x16x32_bf16(alo, wf, oac, 0, 0, 0);
        }
        if (j < Dn) {
            #pragma unroll
            for (int q = 0; q < 4; ++q)
                out[(size_t)(r0 + kg*4 + q)*Dn + j] = oac[q];
        }
    }
}

extern "C" void kernel_launch(void* const* d_in, const int* in_sizes, int n_in,
                              void* d_out, int out_size, void* d_ws, size_t ws_size,
                              hipStream_t stream)
{
    const float* xs = (const float*)d_in[0];
    const float* t  = (const float*)d_in[1];
    const float* W1 = (const float*)d_in[2];
    const float* b1 = (const float*)d_in[3];
    const float* W2 = (const float*)d_in[4];
    const float* b2 = (const float*)d_in[5];
    const float* W3 = (const float*)d_in[6];
    const float* b3 = (const float*)d_in[7];
    float* out = (float*)d_out;

    char* ws = (char*)d_ws;
    unsigned short* W2P = (unsigned short*)(ws);                 // 512 KB
    unsigned short* CmP = (unsigned short*)(ws + 524288);        // 512 KB
    unsigned short* W3P = (unsigned short*)(ws + 1048576);       // 80 KB

    k_pack<<<74,  512,  0, stream>>>(W1, W2, W3, W2P, CmP, W3P);
    k_main<<<256, 1024, 0, stream>>>(xs, t, W1, b1, W2P, CmP, b2, W3P, b3, out);
}